// Round 1
// baseline (313.017 us; speedup 1.0000x reference)
//
#include <hip/hip_runtime.h>
#include <hip/hip_bf16.h>

#define B_   16
#define CIN  256
#define CO   128
#define HW   4096

typedef __attribute__((ext_vector_type(8))) short short8;
typedef __attribute__((ext_vector_type(4))) float f32x4;

__device__ __forceinline__ short f32_to_bf16_rne(float f) {
    union { float f; unsigned u; } v; v.f = f;
    unsigned u = v.u;
    u += 0x7fffu + ((u >> 16) & 1u);
    return (short)(u >> 16);
}

// ---------------------------------------------------------------------------
// Projection: out_T[b][i][co] = sum_ci x[b][ci][i] * w[co][ci] + bias[co]
// grid.x = B * (HW/64) * 2  (bit0 = which of theta/phi), block = 256 (4 waves)
// ---------------------------------------------------------------------------
__global__ __launch_bounds__(256) void proj_kernel(
    const float* __restrict__ xg, const float* __restrict__ xq,
    const float* __restrict__ tw, const float* __restrict__ tb,
    const float* __restrict__ pw, const float* __restrict__ pb,
    short* __restrict__ tT, short* __restrict__ pT)
{
    const int z     = blockIdx.x;
    const int which = z & 1;
    const int itile = (z >> 1) & (HW / 64 - 1);
    const int b     = z >> 7;

    const float* x    = which ? xq : xg;
    const float* w    = which ? pw : tw;
    const float* bias = which ? pb : tb;
    short*       out  = which ? pT : tT;

    const int i0   = itile * 64;
    const int tid  = threadIdx.x;
    const int lane = tid & 63;
    const int wv   = tid >> 6;          // wave 0..3 -> co range [wv*32, wv*32+32)
    const int nrow = lane & 15;
    const int quad = lane >> 4;

    __shared__ short xT[64][72];        // [i_local][ci_chunk] bf16, pad 72 to break banks

    f32x4 acc[4][2] = {};               // 4 m-subtiles (i) x 2 n-subtiles (co)

    float bias_v[2];
    bias_v[0] = bias[wv * 32 + 0  + nrow];
    bias_v[1] = bias[wv * 32 + 16 + nrow];

    const float* xb = x + (long)b * CIN * HW + i0;

    for (int cc = 0; cc < CIN; cc += 64) {
        // ---- stage x chunk [64 ci x 64 i] -> LDS transposed [i][ci] (bf16)
        {
            const int col4 = tid & 15;  // i offset = col4*4
            const int r0   = tid >> 4;  // ci row base
            #pragma unroll
            for (int rr = 0; rr < 4; rr++) {
                const int row = r0 + rr * 16;
                const float4 v = *(const float4*)(xb + (long)(cc + row) * HW + col4 * 4);
                xT[col4 * 4 + 0][row] = f32_to_bf16_rne(v.x);
                xT[col4 * 4 + 1][row] = f32_to_bf16_rne(v.y);
                xT[col4 * 4 + 2][row] = f32_to_bf16_rne(v.z);
                xT[col4 * 4 + 3][row] = f32_to_bf16_rne(v.w);
            }
        }
        __syncthreads();

        #pragma unroll
        for (int ks = 0; ks < 2; ks++) {
            // B-fragments from weights (row-major [co][ci]: 8 contiguous ci per lane)
            short8 bf[2];
            #pragma unroll
            for (int nt = 0; nt < 2; nt++) {
                const float* wp = w + (wv * 32 + nt * 16 + nrow) * CIN + cc + ks * 32 + quad * 8;
                const float4 w0 = ((const float4*)wp)[0];
                const float4 w1 = ((const float4*)wp)[1];
                short8 sv;
                sv[0] = f32_to_bf16_rne(w0.x); sv[1] = f32_to_bf16_rne(w0.y);
                sv[2] = f32_to_bf16_rne(w0.z); sv[3] = f32_to_bf16_rne(w0.w);
                sv[4] = f32_to_bf16_rne(w1.x); sv[5] = f32_to_bf16_rne(w1.y);
                sv[6] = f32_to_bf16_rne(w1.z); sv[7] = f32_to_bf16_rne(w1.w);
                bf[nt] = sv;
            }
            #pragma unroll
            for (int mt = 0; mt < 4; mt++) {
                const short8 a = *(const short8*)&xT[mt * 16 + nrow][ks * 32 + quad * 8];
                acc[mt][0] = __builtin_amdgcn_mfma_f32_16x16x32_bf16(a, bf[0], acc[mt][0], 0, 0, 0);
                acc[mt][1] = __builtin_amdgcn_mfma_f32_16x16x32_bf16(a, bf[1], acc[mt][1], 0, 0, 0);
            }
        }
        __syncthreads();
    }

    // ---- store: D layout col = lane&15 (co), row = quad*4 + reg (i)
    #pragma unroll
    for (int mt = 0; mt < 4; mt++) {
        #pragma unroll
        for (int nt = 0; nt < 2; nt++) {
            const int co = wv * 32 + nt * 16 + nrow;
            #pragma unroll
            for (int r = 0; r < 4; r++) {
                const int il = mt * 16 + quad * 4 + r;
                out[((long)b * HW + i0 + il) * CO + co] =
                    f32_to_bf16_rne(acc[mt][nt][r] + bias_v[nt]);
            }
        }
    }
}

// ---------------------------------------------------------------------------
// Max-GEMM: out[b,i] = sigmoid( max_j ( sum_c tT[b][i][c]*pT[b][j][c] ) / HW )
// grid.x = B * (HW/64), block = 256 (4 waves; wave w owns j = it*64 + w*16 ..)
// ---------------------------------------------------------------------------
__global__ __launch_bounds__(256) void maxgemm_kernel(
    const short* __restrict__ tT, const short* __restrict__ pT,
    float* __restrict__ out)
{
    const int b     = blockIdx.x >> 6;
    const int itile = blockIdx.x & 63;
    const int i0    = itile * 64;
    const int tid   = threadIdx.x;
    const int lane  = tid & 63;
    const int wv    = tid >> 6;
    const int nrow  = lane & 15;
    const int quad  = lane >> 4;

    const short* tbase = tT + ((long)b * HW + i0) * CO;
    const short* pbase = pT + (long)b * HW * CO;

    // loop-invariant A fragments: 64 i x 128 c  (64 VGPRs/lane)
    short8 afrag[4][4];
    #pragma unroll
    for (int mt = 0; mt < 4; mt++)
        #pragma unroll
        for (int ks = 0; ks < 4; ks++)
            afrag[mt][ks] = *(const short8*)(tbase + (mt * 16 + nrow) * CO + ks * 32 + quad * 8);

    f32x4 vmax[4];
    #pragma unroll
    for (int mt = 0; mt < 4; mt++)
        vmax[mt] = (f32x4){-1e30f, -1e30f, -1e30f, -1e30f};

    for (int itj = 0; itj < 64; itj++) {
        const short* pj = pbase + (long)(itj * 64 + wv * 16 + nrow) * CO + quad * 8;
        short8 bfrag[4];
        #pragma unroll
        for (int ks = 0; ks < 4; ks++)
            bfrag[ks] = *(const short8*)(pj + ks * 32);

        #pragma unroll
        for (int mt = 0; mt < 4; mt++) {
            f32x4 acc = {0.f, 0.f, 0.f, 0.f};
            #pragma unroll
            for (int ks = 0; ks < 4; ks++)
                acc = __builtin_amdgcn_mfma_f32_16x16x32_bf16(afrag[mt][ks], bfrag[ks], acc, 0, 0, 0);
            #pragma unroll
            for (int r = 0; r < 4; r++)
                vmax[mt][r] = fmaxf(vmax[mt][r], acc[r]);
        }
    }

    // reduce max across the 16 j-columns (lane&15) via xor-shuffles
    #pragma unroll
    for (int mt = 0; mt < 4; mt++) {
        #pragma unroll
        for (int r = 0; r < 4; r++) {
            float v = vmax[mt][r];
            #pragma unroll
            for (int m = 8; m >= 1; m >>= 1)
                v = fmaxf(v, __shfl_xor(v, m, 64));
            vmax[mt][r] = v;
        }
    }

    __shared__ float smax[64][4];
    if (nrow == 0) {
        #pragma unroll
        for (int mt = 0; mt < 4; mt++)
            #pragma unroll
            for (int r = 0; r < 4; r++)
                smax[mt * 16 + quad * 4 + r][wv] = vmax[mt][r];
    }
    __syncthreads();

    if (tid < 64) {
        float v = fmaxf(fmaxf(smax[tid][0], smax[tid][1]),
                        fmaxf(smax[tid][2], smax[tid][3]));
        v *= (1.0f / (float)HW);
        out[(long)b * HW + i0 + tid] = 1.0f / (1.0f + __expf(-v));
    }
}

extern "C" void kernel_launch(void* const* d_in, const int* in_sizes, int n_in,
                              void* d_out, int out_size, void* d_ws, size_t ws_size,
                              hipStream_t stream) {
    const float* xg = (const float*)d_in[0];
    const float* xq = (const float*)d_in[1];
    const float* tw = (const float*)d_in[2];
    const float* tb = (const float*)d_in[3];
    const float* pw = (const float*)d_in[4];
    const float* pb = (const float*)d_in[5];
    float* out = (float*)d_out;

    short* tT = (short*)d_ws;                       // [B][HW][CO] bf16, 16.78 MB
    short* pT = tT + (size_t)B_ * HW * CO;          // [B][HW][CO] bf16, 16.78 MB

    proj_kernel<<<B_ * (HW / 64) * 2, 256, 0, stream>>>(xg, xq, tw, tb, pw, pb, tT, pT);
    maxgemm_kernel<<<B_ * (HW / 64), 256, 0, stream>>>(tT, pT, out);
}

// Round 2
// 298.667 us; speedup vs baseline: 1.0480x; 1.0480x over previous
//
#include <hip/hip_runtime.h>
#include <hip/hip_bf16.h>

#define B_   16
#define CIN  256
#define CO   128
#define HW   4096

typedef __attribute__((ext_vector_type(8))) short short8;
typedef __attribute__((ext_vector_type(4))) float f32x4;

__device__ __forceinline__ short f32_to_bf16_rne(float f) {
    union { float f; unsigned u; } v; v.f = f;
    unsigned u = v.u;
    u += 0x7fffu + ((u >> 16) & 1u);
    return (short)(u >> 16);
}

// ---------------------------------------------------------------------------
// Projection: out_T[b][i][co] = sum_ci x[b][ci][i] * w[co][ci] + bias[co]
// grid.x = B * (HW/64) * 2  (bit0 = theta/phi), block = 256 (4 waves)
// Software-pipelined: global loads for chunk cc+1 issued during MFMA of cc.
// ---------------------------------------------------------------------------
__global__ __launch_bounds__(256) void proj_kernel(
    const float* __restrict__ xg, const float* __restrict__ xq,
    const float* __restrict__ tw, const float* __restrict__ tb,
    const float* __restrict__ pw, const float* __restrict__ pb,
    short* __restrict__ tT, short* __restrict__ pT)
{
    const int z     = blockIdx.x;
    const int which = z & 1;
    const int itile = (z >> 1) & (HW / 64 - 1);
    const int b     = z >> 7;

    const float* x    = which ? xq : xg;
    const float* w    = which ? pw : tw;
    const float* bias = which ? pb : tb;
    short*       out  = which ? pT : tT;

    const int i0   = itile * 64;
    const int tid  = threadIdx.x;
    const int lane = tid & 63;
    const int wv   = tid >> 6;          // wave 0..3 -> co range [wv*32, wv*32+32)
    const int nrow = lane & 15;
    const int quad = lane >> 4;

    const int col4 = tid & 15;          // i group (4 consecutive i)
    const int rp   = tid >> 4;          // row-pair index 0..15

    __shared__ short xT[64][72];        // [i_local][ci_chunk] bf16 (72: 144B row, 16B-divisible)

    f32x4 acc[4][2] = {};               // 4 m-subtiles (i) x 2 n-subtiles (co)

    float bias_v[2];
    bias_v[0] = bias[wv * 32 + 0  + nrow];
    bias_v[1] = bias[wv * 32 + 16 + nrow];

    const float* xb = x + (long)b * CIN * HW + i0;

    float4 cva[2], cvb[2];              // pipeline regs: row pairs (even, odd) x 2 rr

    auto load_chunk = [&](int cc) {
        #pragma unroll
        for (int rr = 0; rr < 2; rr++) {
            const int row = rr * 32 + rp * 2;
            cva[rr] = *(const float4*)(xb + (long)(cc + row)     * HW + col4 * 4);
            cvb[rr] = *(const float4*)(xb + (long)(cc + row + 1) * HW + col4 * 4);
        }
    };
    auto store_chunk = [&]() {
        #pragma unroll
        for (int rr = 0; rr < 2; rr++) {
            const int row = rr * 32 + rp * 2;
            const float* pa = (const float*)&cva[rr];
            const float* pb2 = (const float*)&cvb[rr];
            #pragma unroll
            for (int k = 0; k < 4; k++) {
                const unsigned lo = (unsigned short)f32_to_bf16_rne(pa[k]);
                const unsigned hi = (unsigned short)f32_to_bf16_rne(pb2[k]);
                *(unsigned*)&xT[col4 * 4 + k][row] = lo | (hi << 16);
            }
        }
    };
    auto mfma_chunk = [&](int cc) {
        #pragma unroll
        for (int ks = 0; ks < 2; ks++) {
            short8 bfv[2];
            #pragma unroll
            for (int nt = 0; nt < 2; nt++) {
                const float* wp = w + (wv * 32 + nt * 16 + nrow) * CIN + cc + ks * 32 + quad * 8;
                const float4 w0 = ((const float4*)wp)[0];
                const float4 w1 = ((const float4*)wp)[1];
                short8 sv;
                sv[0] = f32_to_bf16_rne(w0.x); sv[1] = f32_to_bf16_rne(w0.y);
                sv[2] = f32_to_bf16_rne(w0.z); sv[3] = f32_to_bf16_rne(w0.w);
                sv[4] = f32_to_bf16_rne(w1.x); sv[5] = f32_to_bf16_rne(w1.y);
                sv[6] = f32_to_bf16_rne(w1.z); sv[7] = f32_to_bf16_rne(w1.w);
                bfv[nt] = sv;
            }
            #pragma unroll
            for (int mt = 0; mt < 4; mt++) {
                const short8 a = *(const short8*)&xT[mt * 16 + nrow][ks * 32 + quad * 8];
                acc[mt][0] = __builtin_amdgcn_mfma_f32_16x16x32_bf16(a, bfv[0], acc[mt][0], 0, 0, 0);
                acc[mt][1] = __builtin_amdgcn_mfma_f32_16x16x32_bf16(a, bfv[1], acc[mt][1], 0, 0, 0);
            }
        }
    };

    load_chunk(0);
    #pragma unroll
    for (int cc = 0; cc < CIN; cc += 64) {
        if (cc) __syncthreads();        // prior MFMA reads done before overwrite
        store_chunk();
        __syncthreads();
        if (cc + 64 < CIN) load_chunk(cc + 64);   // prefetch overlaps MFMA below
        mfma_chunk(cc);
    }

    // ---- store: D layout col = lane&15 (co), row = quad*4 + reg (i)
    #pragma unroll
    for (int mt = 0; mt < 4; mt++) {
        #pragma unroll
        for (int nt = 0; nt < 2; nt++) {
            const int co = wv * 32 + nt * 16 + nrow;
            #pragma unroll
            for (int r = 0; r < 4; r++) {
                const int il = mt * 16 + quad * 4 + r;
                out[((long)b * HW + i0 + il) * CO + co] =
                    f32_to_bf16_rne(acc[mt][nt][r] + bias_v[nt]);
            }
        }
    }
}

// ---------------------------------------------------------------------------
// Max-GEMM: out[b,i] = sigmoid( max_j ( sum_c tT[b][i][c]*pT[b][j][c] ) / HW )
// grid.x = B * (HW/64), block = 256. XCD-swizzled: batch b -> XCD b%8 so each
// batch's p (1 MB) stays L2-resident on one XCD (2 batches/XCD = 2 MB < 4 MiB).
// Register double-buffer prefetch; 2 j-subtiles (32 MFMA) per iteration; no
// barriers in the main loop.
// ---------------------------------------------------------------------------
__global__ __launch_bounds__(256) void maxgemm_kernel(
    const short* __restrict__ tT, const short* __restrict__ pT,
    float* __restrict__ out)
{
    const int n     = blockIdx.x;
    const int xcd   = n & 7;
    const int idx   = n >> 3;            // 0..127
    const int b     = xcd + 8 * (idx & 1);
    const int itile = idx >> 1;          // 0..63
    const int i0    = itile * 64;
    const int tid   = threadIdx.x;
    const int lane  = tid & 63;
    const int wv    = tid >> 6;
    const int nrow  = lane & 15;
    const int quad  = lane >> 4;

    const short* tbase = tT + ((long)b * HW + i0) * CO;
    const short* pbase = pT + (long)b * HW * CO
                       + (long)(wv * 32 + nrow) * CO + quad * 8;

    // loop-invariant A fragments: 64 i x 128 c  (64 VGPRs/lane)
    short8 afrag[4][4];
    #pragma unroll
    for (int mt = 0; mt < 4; mt++)
        #pragma unroll
        for (int ks = 0; ks < 4; ks++)
            afrag[mt][ks] = *(const short8*)(tbase + (mt * 16 + nrow) * CO + ks * 32 + quad * 8);

    f32x4 vmax[4];
    #pragma unroll
    for (int mt = 0; mt < 4; mt++)
        vmax[mt] = (f32x4){-1e30f, -1e30f, -1e30f, -1e30f};

    short8 bf0[2][4], bf1[2][4];

    auto load_tile = [&](int itj, short8 (*dst)[4]) {
        const short* p2 = pbase + (long)itj * 128 * CO;
        #pragma unroll
        for (int nt = 0; nt < 2; nt++)
            #pragma unroll
            for (int ks = 0; ks < 4; ks++)
                dst[nt][ks] = *(const short8*)(p2 + nt * 16 * CO + ks * 32);
    };
    auto compute = [&](short8 (*bf)[4]) {
        #pragma unroll
        for (int mt = 0; mt < 4; mt++) {
            #pragma unroll
            for (int nt = 0; nt < 2; nt++) {
                f32x4 acc = {0.f, 0.f, 0.f, 0.f};
                #pragma unroll
                for (int ks = 0; ks < 4; ks++)
                    acc = __builtin_amdgcn_mfma_f32_16x16x32_bf16(afrag[mt][ks], bf[nt][ks], acc, 0, 0, 0);
                #pragma unroll
                for (int r = 0; r < 4; r++)
                    vmax[mt][r] = fmaxf(vmax[mt][r], acc[r]);
            }
        }
    };

    load_tile(0, bf0);
    for (int itj = 0; itj < 32; itj += 2) {
        load_tile(itj + 1, bf1);                       // prefetch (itj+1 <= 31 always valid)
        compute(bf0);
        load_tile((itj + 2 < 32) ? itj + 2 : 0, bf0);  // clamped dummy on last iter
        compute(bf1);
    }

    // reduce max across the 16 j-columns (lane bits 0-3) via xor-shuffles
    #pragma unroll
    for (int mt = 0; mt < 4; mt++) {
        #pragma unroll
        for (int r = 0; r < 4; r++) {
            float v = vmax[mt][r];
            #pragma unroll
            for (int m = 8; m >= 1; m >>= 1)
                v = fmaxf(v, __shfl_xor(v, m, 64));
            vmax[mt][r] = v;
        }
    }

    __shared__ float smax[64][4];
    if (nrow == 0) {
        #pragma unroll
        for (int mt = 0; mt < 4; mt++)
            #pragma unroll
            for (int r = 0; r < 4; r++)
                smax[mt * 16 + quad * 4 + r][wv] = vmax[mt][r];
    }
    __syncthreads();

    if (tid < 64) {
        float v = fmaxf(fmaxf(smax[tid][0], smax[tid][1]),
                        fmaxf(smax[tid][2], smax[tid][3]));
        v *= (1.0f / (float)HW);
        out[(long)b * HW + i0 + tid] = 1.0f / (1.0f + __expf(-v));
    }
}

extern "C" void kernel_launch(void* const* d_in, const int* in_sizes, int n_in,
                              void* d_out, int out_size, void* d_ws, size_t ws_size,
                              hipStream_t stream) {
    const float* xg = (const float*)d_in[0];
    const float* xq = (const float*)d_in[1];
    const float* tw = (const float*)d_in[2];
    const float* tb = (const float*)d_in[3];
    const float* pw = (const float*)d_in[4];
    const float* pb = (const float*)d_in[5];
    float* out = (float*)d_out;

    short* tT = (short*)d_ws;                       // [B][HW][CO] bf16, 16.78 MB
    short* pT = tT + (size_t)B_ * HW * CO;          // [B][HW][CO] bf16, 16.78 MB

    proj_kernel<<<B_ * (HW / 64) * 2, 256, 0, stream>>>(xg, xq, tw, tb, pw, pb, tT, pT);
    maxgemm_kernel<<<B_ * (HW / 64), 256, 0, stream>>>(tT, pT, out);
}

// Round 4
// 293.706 us; speedup vs baseline: 1.0657x; 1.0169x over previous
//
#include <hip/hip_runtime.h>
#include <hip/hip_bf16.h>

#define B_   16
#define CIN  256
#define CO   128
#define HW   4096

typedef __attribute__((ext_vector_type(8))) short short8;
typedef __attribute__((ext_vector_type(4))) float f32x4;

__device__ __forceinline__ short f32_to_bf16_rne(float f) {
    union { float f; unsigned u; } v; v.f = f;
    unsigned u = v.u;
    u += 0x7fffu + ((u >> 16) & 1u);
    return (short)(u >> 16);
}

// ---------------------------------------------------------------------------
// Projection: out_T[b][i][co] = sum_ci x[b][ci][i] * w[co][ci] + bias[co]
// grid.x = B * (HW/64) * 2, block = 256 (4 waves).
// Dual LDS buffer, ONE barrier per chunk: sync -> prefetch(k+1) -> mfma(k)
// -> cvt+store(k+1 -> other buf). Prefetch loads stay in flight across the
// MFMA phase (no vmcnt drain between issue and use).
// Lane map col4=tid&15: 16 consecutive lanes read 256B contiguous (coalesced).
// ---------------------------------------------------------------------------
__global__ __launch_bounds__(256) void proj_kernel(
    const float* __restrict__ xg, const float* __restrict__ xq,
    const float* __restrict__ tw, const float* __restrict__ tb,
    const float* __restrict__ pw, const float* __restrict__ pb,
    short* __restrict__ tT, short* __restrict__ pT)
{
    const int z     = blockIdx.x;
    const int which = z & 1;
    const int itile = (z >> 1) & (HW / 64 - 1);
    const int b     = z >> 7;

    const float* x    = which ? xq : xg;
    const float* w    = which ? pw : tw;
    const float* bias = which ? pb : tb;
    short*       out  = which ? pT : tT;

    const int i0   = itile * 64;
    const int tid  = threadIdx.x;
    const int lane = tid & 63;
    const int wv   = tid >> 6;          // wave 0..3 -> co range [wv*32, wv*32+32)
    const int nrow = lane & 15;
    const int quad = lane >> 4;

    const int col4 = tid & 15;          // i group (4 consecutive i) -> coalesced loads
    const int rp   = tid >> 4;          // row-pair index 0..15

    __shared__ short xT[2][64][72];     // [buf][i][ci], 72-short rows (144B, 16B-divisible)

    f32x4 acc[4][2] = {};               // 4 m-subtiles (i) x 2 n-subtiles (co)

    float bias_v[2];
    bias_v[0] = bias[wv * 32 + 0  + nrow];
    bias_v[1] = bias[wv * 32 + 16 + nrow];

    const float* xb = x + (long)b * CIN * HW + i0;

    float4 cva[2], cvb[2];              // pipeline regs (rows rp*2, rp*2+1 in two rr halves)

    auto load_chunk = [&](int cc) {
        #pragma unroll
        for (int rr = 0; rr < 2; rr++) {
            const int row = rr * 32 + rp * 2;
            cva[rr] = *(const float4*)(xb + (long)(cc + row)     * HW + col4 * 4);
            cvb[rr] = *(const float4*)(xb + (long)(cc + row + 1) * HW + col4 * 4);
        }
    };
    auto store_chunk = [&](int buf) {
        #pragma unroll
        for (int rr = 0; rr < 2; rr++) {
            const int row = rr * 32 + rp * 2;
            const float* pa  = (const float*)&cva[rr];
            const float* pb2 = (const float*)&cvb[rr];
            #pragma unroll
            for (int k = 0; k < 4; k++) {
                const unsigned lo = (unsigned short)f32_to_bf16_rne(pa[k]);
                const unsigned hi = (unsigned short)f32_to_bf16_rne(pb2[k]);
                *(unsigned*)&xT[buf][col4 * 4 + k][row] = lo | (hi << 16);
            }
        }
    };
    auto mfma_chunk = [&](int cc, int buf) {
        #pragma unroll
        for (int ks = 0; ks < 2; ks++) {
            short8 bfv[2];
            #pragma unroll
            for (int nt = 0; nt < 2; nt++) {
                const float* wp = w + (wv * 32 + nt * 16 + nrow) * CIN + cc + ks * 32 + quad * 8;
                const float4 w0 = ((const float4*)wp)[0];
                const float4 w1 = ((const float4*)wp)[1];
                short8 sv;
                sv[0] = f32_to_bf16_rne(w0.x); sv[1] = f32_to_bf16_rne(w0.y);
                sv[2] = f32_to_bf16_rne(w0.z); sv[3] = f32_to_bf16_rne(w0.w);
                sv[4] = f32_to_bf16_rne(w1.x); sv[5] = f32_to_bf16_rne(w1.y);
                sv[6] = f32_to_bf16_rne(w1.z); sv[7] = f32_to_bf16_rne(w1.w);
                bfv[nt] = sv;
            }
            #pragma unroll
            for (int mt = 0; mt < 4; mt++) {
                const short8 a = *(const short8*)&xT[buf][mt * 16 + nrow][ks * 32 + quad * 8];
                acc[mt][0] = __builtin_amdgcn_mfma_f32_16x16x32_bf16(a, bfv[0], acc[mt][0], 0, 0, 0);
                acc[mt][1] = __builtin_amdgcn_mfma_f32_16x16x32_bf16(a, bfv[1], acc[mt][1], 0, 0, 0);
            }
        }
    };

    load_chunk(0);
    store_chunk(0);
    #pragma unroll
    for (int c4 = 0; c4 < 4; c4++) {
        __syncthreads();
        if (c4 < 3) load_chunk(c4 * 64 + 64);      // prefetch: consumed only after mfma below
        mfma_chunk(c4 * 64, c4 & 1);
        if (c4 < 3) store_chunk((c4 + 1) & 1);     // other buffer; prev reads barrier-protected
    }

    // ---- store: D layout col = lane&15 (co), row = quad*4 + reg (i)
    #pragma unroll
    for (int mt = 0; mt < 4; mt++) {
        #pragma unroll
        for (int nt = 0; nt < 2; nt++) {
            const int co = wv * 32 + nt * 16 + nrow;
            #pragma unroll
            for (int r = 0; r < 4; r++) {
                const int il = mt * 16 + quad * 4 + r;
                out[((long)b * HW + i0 + il) * CO + co] =
                    f32_to_bf16_rne(acc[mt][nt][r] + bias_v[nt]);
            }
        }
    }
}

// ---------------------------------------------------------------------------
// Max-GEMM: out[b,i] = sigmoid( max_j ( sum_c tT[b][i][c]*pT[b][j][c] ) / HW )
// grid.x = B * (HW/64), block = 256, XCD-swizzled (batch -> XCD, p L2-resident).
// A tile (64i x 128c, shared by all 4 waves) in LDS; B tiles register
// double-buffered (64 VGPR). Low register pressure -> buffers stay in VGPRs,
// 4 blocks/CU co-reside, loads overlap MFMA with no barriers in the loop.
// ---------------------------------------------------------------------------
__global__ __launch_bounds__(256) void maxgemm_kernel(
    const short* __restrict__ tT, const short* __restrict__ pT,
    float* __restrict__ out)
{
    const int n     = blockIdx.x;
    const int xcd   = n & 7;
    const int idx   = n >> 3;            // 0..127
    const int b     = xcd + 8 * (idx & 1);
    const int itile = idx >> 1;          // 0..63
    const int i0    = itile * 64;
    const int tid   = threadIdx.x;
    const int lane  = tid & 63;
    const int wv    = tid >> 6;
    const int nrow  = lane & 15;
    const int quad  = lane >> 4;

    __shared__ short aT[64][136];        // [i][c], 272B rows
    __shared__ float smax[64][4];

    const short* tbase = tT + ((long)b * HW + i0) * CO;
    const short* pbase = pT + (long)b * HW * CO
                       + (long)(wv * 32 + nrow) * CO + quad * 8;

    // ---- stage A tile: 64 rows x 128 c = 1024 16B-chunks, 256 thr x 4
    {
        const int chunk = tid & 15;      // 16B chunk (8 shorts) within row
        const int row0  = tid >> 4;      // 0..15
        #pragma unroll
        for (int r = 0; r < 4; r++) {
            const int row = row0 + r * 16;
            const short8 v = *(const short8*)(tbase + (long)row * CO + chunk * 8);
            *(short8*)&aT[row][chunk * 8] = v;
        }
    }
    __syncthreads();

    f32x4 vmax[4];
    #pragma unroll
    for (int mt = 0; mt < 4; mt++)
        vmax[mt] = (f32x4){-1e30f, -1e30f, -1e30f, -1e30f};

    short8 bf0[2][4], bf1[2][4];

    auto load_tile = [&](int itj, short8 (*dst)[4]) {
        const short* p2 = pbase + (long)itj * 128 * CO;
        #pragma unroll
        for (int nt = 0; nt < 2; nt++)
            #pragma unroll
            for (int ks = 0; ks < 4; ks++)
                dst[nt][ks] = *(const short8*)(p2 + nt * 16 * CO + ks * 32);
    };
    auto compute = [&](short8 (*bf)[4]) {
        #pragma unroll
        for (int mt = 0; mt < 4; mt++) {
            f32x4 acc0 = {0.f, 0.f, 0.f, 0.f};
            f32x4 acc1 = {0.f, 0.f, 0.f, 0.f};
            #pragma unroll
            for (int ks = 0; ks < 4; ks++) {
                const short8 a = *(const short8*)&aT[mt * 16 + nrow][ks * 32 + quad * 8];
                acc0 = __builtin_amdgcn_mfma_f32_16x16x32_bf16(a, bf[0][ks], acc0, 0, 0, 0);
                acc1 = __builtin_amdgcn_mfma_f32_16x16x32_bf16(a, bf[1][ks], acc1, 0, 0, 0);
            }
            #pragma unroll
            for (int r = 0; r < 4; r++)
                vmax[mt][r] = fmaxf(vmax[mt][r], fmaxf(acc0[r], acc1[r]));
        }
    };

    load_tile(0, bf0);
    for (int itj = 0; itj < 32; itj += 2) {
        load_tile(itj + 1, bf1);                       // prefetch
        compute(bf0);
        load_tile((itj + 2 < 32) ? itj + 2 : 0, bf0);  // clamped dummy on last iter
        compute(bf1);
    }

    // reduce max across the 16 j-columns (lane bits 0-3) via xor-shuffles
    #pragma unroll
    for (int mt = 0; mt < 4; mt++) {
        #pragma unroll
        for (int r = 0; r < 4; r++) {
            float v = vmax[mt][r];
            #pragma unroll
            for (int m = 8; m >= 1; m >>= 1)
                v = fmaxf(v, __shfl_xor(v, m, 64));
            vmax[mt][r] = v;
        }
    }

    if (nrow == 0) {
        #pragma unroll
        for (int mt = 0; mt < 4; mt++)
            #pragma unroll
            for (int r = 0; r < 4; r++)
                smax[mt * 16 + quad * 4 + r][wv] = vmax[mt][r];
    }
    __syncthreads();

    if (tid < 64) {
        float v = fmaxf(fmaxf(smax[tid][0], smax[tid][1]),
                        fmaxf(smax[tid][2], smax[tid][3]));
        v *= (1.0f / (float)HW);
        out[(long)b * HW + i0 + tid] = 1.0f / (1.0f + __expf(-v));
    }
}

extern "C" void kernel_launch(void* const* d_in, const int* in_sizes, int n_in,
                              void* d_out, int out_size, void* d_ws, size_t ws_size,
                              hipStream_t stream) {
    const float* xg = (const float*)d_in[0];
    const float* xq = (const float*)d_in[1];
    const float* tw = (const float*)d_in[2];
    const float* tb = (const float*)d_in[3];
    const float* pw = (const float*)d_in[4];
    const float* pb = (const float*)d_in[5];
    float* out = (float*)d_out;

    short* tT = (short*)d_ws;                       // [B][HW][CO] bf16, 16.78 MB
    short* pT = tT + (size_t)B_ * HW * CO;          // [B][HW][CO] bf16, 16.78 MB

    proj_kernel<<<B_ * (HW / 64) * 2, 256, 0, stream>>>(xg, xq, tw, tb, pw, pb, tT, pT);
    maxgemm_kernel<<<B_ * (HW / 64), 256, 0, stream>>>(tT, pT, out);
}

// Round 5
// 250.509 us; speedup vs baseline: 1.2495x; 1.1724x over previous
//
#include <hip/hip_runtime.h>
#include <hip/hip_bf16.h>

#define B_   16
#define CIN  256
#define CO   128
#define HW   4096

typedef __attribute__((ext_vector_type(8))) short short8;
typedef __attribute__((ext_vector_type(4))) float f32x4;

__device__ __forceinline__ short f32_to_bf16_rne(float f) {
    union { float f; unsigned u; } v; v.f = f;
    unsigned u = v.u;
    u += 0x7fffu + ((u >> 16) & 1u);
    return (short)(u >> 16);
}

// ---------------------------------------------------------------------------
// Weight pre-convert: wbf[0][co][ci] = bf16(theta_w), wbf[1][co][ci] = bf16(phi_w)
// ---------------------------------------------------------------------------
__global__ __launch_bounds__(256) void wconv_kernel(
    const float* __restrict__ tw, const float* __restrict__ pw,
    short* __restrict__ wbf)
{
    const int idx = blockIdx.x * 256 + threadIdx.x;     // 0 .. 2*CO*CIN-1
    const float v = (idx < CO * CIN) ? tw[idx] : pw[idx - CO * CIN];
    wbf[idx] = f32_to_bf16_rne(v);
}

// ---------------------------------------------------------------------------
// Projection: out_T[b][i][co] = sum_ci x[b][ci][i] * w[co][ci] + bias[co]
// grid.x = 2048, block = 256 (4 waves). XCD-swizzled: batch b runs on XCD b%8
// so tT/pT lines are dirty-local to the XCD that maxgemm will read them from.
// Weight fragments preloaded to registers (64 VGPR, bf16 from ws) -- K-loop
// body is pure x-stream: global load -> cvt -> LDS -> MFMA, dual-buffered,
// one barrier per chunk.
// ---------------------------------------------------------------------------
__global__ __launch_bounds__(256, 3) void proj_kernel(
    const float* __restrict__ xg, const float* __restrict__ xq,
    const float* __restrict__ tb, const float* __restrict__ pb,
    const short* __restrict__ wbf,
    short* __restrict__ tT, short* __restrict__ pT)
{
    const int n     = blockIdx.x;
    const int xcd   = n & 7;
    const int q     = n >> 3;            // 0..255
    const int b     = xcd + 8 * (q & 1);
    const int r2    = q >> 1;            // 0..127
    const int which = r2 & 1;
    const int itile = r2 >> 1;           // 0..63

    const float* x    = which ? xq : xg;
    const float* bias = which ? pb : tb;
    const short* wb   = wbf + which * CO * CIN;
    short*       out  = which ? pT : tT;

    const int i0   = itile * 64;
    const int tid  = threadIdx.x;
    const int lane = tid & 63;
    const int wv   = tid >> 6;          // wave 0..3 -> co range [wv*32, wv*32+32)
    const int nrow = lane & 15;
    const int quad = lane >> 4;

    const int col4 = tid & 15;          // i group (4 consecutive i) -> coalesced loads
    const int rp   = tid >> 4;          // row-pair index 0..15

    __shared__ short xT[2][64][72];     // [buf][i][ci], 144B rows (16B-divisible)

    f32x4 acc[4][2] = {};               // 4 m-subtiles (i) x 2 n-subtiles (co)

    float bias_v[2];
    bias_v[0] = bias[wv * 32 + 0  + nrow];
    bias_v[1] = bias[wv * 32 + 16 + nrow];

    // ---- preload ALL weight fragments (this wave's 32 co x 256 ci): 64 VGPRs
    short8 wfrag[4][2][2];              // [c4][ks][nt]
    #pragma unroll
    for (int c4 = 0; c4 < 4; c4++)
        #pragma unroll
        for (int ks = 0; ks < 2; ks++)
            #pragma unroll
            for (int nt = 0; nt < 2; nt++)
                wfrag[c4][ks][nt] = *(const short8*)(
                    wb + (wv * 32 + nt * 16 + nrow) * CIN + c4 * 64 + ks * 32 + quad * 8);

    const float* xb = x + (long)b * CIN * HW + i0;

    float4 cva[2], cvb[2];              // pipeline regs

    auto load_chunk = [&](int cc) {
        #pragma unroll
        for (int rr = 0; rr < 2; rr++) {
            const int row = rr * 32 + rp * 2;
            cva[rr] = *(const float4*)(xb + (long)(cc + row)     * HW + col4 * 4);
            cvb[rr] = *(const float4*)(xb + (long)(cc + row + 1) * HW + col4 * 4);
        }
    };
    auto store_chunk = [&](int buf) {
        #pragma unroll
        for (int rr = 0; rr < 2; rr++) {
            const int row = rr * 32 + rp * 2;
            const float* pa  = (const float*)&cva[rr];
            const float* pb2 = (const float*)&cvb[rr];
            #pragma unroll
            for (int k = 0; k < 4; k++) {
                const unsigned lo = (unsigned short)f32_to_bf16_rne(pa[k]);
                const unsigned hi = (unsigned short)f32_to_bf16_rne(pb2[k]);
                *(unsigned*)&xT[buf][col4 * 4 + k][row] = lo | (hi << 16);
            }
        }
    };
    auto mfma_chunk = [&](int c4, int buf) {
        #pragma unroll
        for (int ks = 0; ks < 2; ks++)
            #pragma unroll
            for (int mt = 0; mt < 4; mt++) {
                const short8 a = *(const short8*)&xT[buf][mt * 16 + nrow][ks * 32 + quad * 8];
                acc[mt][0] = __builtin_amdgcn_mfma_f32_16x16x32_bf16(a, wfrag[c4][ks][0], acc[mt][0], 0, 0, 0);
                acc[mt][1] = __builtin_amdgcn_mfma_f32_16x16x32_bf16(a, wfrag[c4][ks][1], acc[mt][1], 0, 0, 0);
            }
    };

    load_chunk(0);
    store_chunk(0);
    #pragma unroll
    for (int c4 = 0; c4 < 4; c4++) {
        __syncthreads();
        if (c4 < 3) load_chunk(c4 * 64 + 64);      // prefetch overlaps MFMA below
        mfma_chunk(c4, c4 & 1);
        if (c4 < 3) store_chunk((c4 + 1) & 1);
    }

    // ---- store: D layout col = lane&15 (co), row = quad*4 + reg (i)
    #pragma unroll
    for (int mt = 0; mt < 4; mt++)
        #pragma unroll
        for (int nt = 0; nt < 2; nt++) {
            const int co = wv * 32 + nt * 16 + nrow;
            #pragma unroll
            for (int r = 0; r < 4; r++) {
                const int il = mt * 16 + quad * 4 + r;
                out[((long)b * HW + i0 + il) * CO + co] =
                    f32_to_bf16_rne(acc[mt][nt][r] + bias_v[nt]);
            }
        }
}

// ---------------------------------------------------------------------------
// Max-GEMM: out[b,i] = sigmoid( max_j ( sum_c tT[b][i][c]*pT[b][j][c] ) / HW )
// grid.x = 256 (1 block/CU), block = 256 (4 waves). XCD-swizzled to match proj.
// i-tile 256/block: wave w owns i = i0+wv*64.. (A = 64 VGPRs, loop-invariant).
// B j-tile (64x128) staged to LDS shared by all 4 waves, double-buffered,
// XOR-swizzled 16B chunks (no padding) for conflict-free b128 access.
// ds:MFMA = 16:64 per iteration -> MFMA is the busiest pipe.
// ---------------------------------------------------------------------------
__global__ __launch_bounds__(256, 1) void maxgemm_kernel(
    const short* __restrict__ tT, const short* __restrict__ pT,
    float* __restrict__ out)
{
    const int n     = blockIdx.x;
    const int b     = (n & 7) + 8 * ((n >> 3) & 1);
    const int itile = n >> 4;            // 0..15
    const int i0    = itile * 256;
    const int tid   = threadIdx.x;
    const int lane  = tid & 63;
    const int wv    = tid >> 6;
    const int nrow  = lane & 15;
    const int quad  = lane >> 4;

    __shared__ short bT[2][64][128];     // 32 KB, unpadded, XOR-swizzled chunks

    // ---- loop-invariant A fragments: this wave's 64 i x 128 c (64 VGPRs)
    short8 afrag[4][4];
    {
        const short* tb2 = tT + ((long)b * HW + i0 + wv * 64) * CO;
        #pragma unroll
        for (int mt = 0; mt < 4; mt++)
            #pragma unroll
            for (int ks = 0; ks < 4; ks++)
                afrag[mt][ks] = *(const short8*)(tb2 + (mt * 16 + nrow) * CO + ks * 32 + quad * 8);
    }

    const short* pb2 = pT + (long)b * HW * CO;
    const int sc8 = tid & 15;            // 16B chunk within row
    const int sj0 = tid >> 4;            // 0..15

    short8 sreg[4];
    auto stage_load = [&](int jt) {      // global -> regs (coalesced 256B segs)
        const short* src = pb2 + (long)jt * 64 * CO;
        #pragma unroll
        for (int r = 0; r < 4; r++)
            sreg[r] = *(const short8*)(src + (sj0 + r * 16) * CO + sc8 * 8);
    };
    auto stage_write = [&](int buf) {    // regs -> LDS, swizzled chunk
        #pragma unroll
        for (int r = 0; r < 4; r++) {
            const int j  = sj0 + r * 16;
            const int c8 = sc8 ^ (j & 7);
            *(short8*)&bT[buf][j][c8 * 8] = sreg[r];
        }
    };

    f32x4 vmax[4];
    #pragma unroll
    for (int mt = 0; mt < 4; mt++)
        vmax[mt] = (f32x4){-1e30f, -1e30f, -1e30f, -1e30f};

    auto compute = [&](int buf) {
        #pragma unroll
        for (int nt = 0; nt < 4; nt++) {
            short8 bf[4];
            const int j = nt * 16 + nrow;
            #pragma unroll
            for (int ks = 0; ks < 4; ks++) {
                const int c8 = (ks * 4 + quad) ^ (j & 7);
                bf[ks] = *(const short8*)&bT[buf][j][c8 * 8];
            }
            #pragma unroll
            for (int mt = 0; mt < 4; mt++) {
                f32x4 acc = {0.f, 0.f, 0.f, 0.f};
                #pragma unroll
                for (int ks = 0; ks < 4; ks++)
                    acc = __builtin_amdgcn_mfma_f32_16x16x32_bf16(afrag[mt][ks], bf[ks], acc, 0, 0, 0);
                #pragma unroll
                for (int r = 0; r < 4; r++)
                    vmax[mt][r] = fmaxf(vmax[mt][r], acc[r]);
            }
        }
    };

    stage_load(0);
    stage_write(0);
    for (int jt = 0; jt < 64; jt++) {
        __syncthreads();
        if (jt < 63) stage_load(jt + 1);     // prefetch overlaps MFMA below
        compute(jt & 1);
        if (jt < 63) stage_write((jt + 1) & 1);
    }

    // ---- reduce max over 16 j-columns (lane bits 0-3); each wave owns its 64 i
    #pragma unroll
    for (int mt = 0; mt < 4; mt++)
        #pragma unroll
        for (int r = 0; r < 4; r++) {
            float v = vmax[mt][r];
            #pragma unroll
            for (int m = 8; m >= 1; m >>= 1)
                v = fmaxf(v, __shfl_xor(v, m, 64));
            vmax[mt][r] = v;
        }

    if (nrow == 0) {
        #pragma unroll
        for (int mt = 0; mt < 4; mt++)
            #pragma unroll
            for (int r = 0; r < 4; r++) {
                const float v = vmax[mt][r] * (1.0f / (float)HW);
                out[(long)b * HW + i0 + wv * 64 + mt * 16 + quad * 4 + r] =
                    1.0f / (1.0f + __expf(-v));
            }
    }
}

extern "C" void kernel_launch(void* const* d_in, const int* in_sizes, int n_in,
                              void* d_out, int out_size, void* d_ws, size_t ws_size,
                              hipStream_t stream) {
    const float* xg = (const float*)d_in[0];
    const float* xq = (const float*)d_in[1];
    const float* tw = (const float*)d_in[2];
    const float* tb = (const float*)d_in[3];
    const float* pw = (const float*)d_in[4];
    const float* pb = (const float*)d_in[5];
    float* out = (float*)d_out;

    short* tT  = (short*)d_ws;                         // [B][HW][CO] bf16, 16.78 MB
    short* pT  = tT + (size_t)B_ * HW * CO;            // [B][HW][CO] bf16, 16.78 MB
    short* wbf = pT + (size_t)B_ * HW * CO;            // [2][CO][CIN] bf16, 131 KB

    wconv_kernel<<<(2 * CO * CIN) / 256, 256, 0, stream>>>(tw, pw, wbf);
    proj_kernel<<<B_ * (HW / 64) * 2, 256, 0, stream>>>(xg, xq, tb, pb, wbf, tT, pT);
    maxgemm_kernel<<<B_ * (HW / 256), 256, 0, stream>>>(tT, pT, out);
}